// Round 5
// baseline (131.581 us; speedup 1.0000x reference)
//
#include <hip/hip_runtime.h>

typedef __attribute__((ext_vector_type(4))) float f32x4;
typedef __attribute__((ext_vector_type(16))) float f32x16;
typedef __attribute__((ext_vector_type(8))) __bf16 bf16x8;
typedef __attribute__((ext_vector_type(4))) unsigned short u16x4;
typedef __attribute__((ext_vector_type(2))) unsigned int u32x2;

#define DEVI static __device__ __forceinline__

DEVI unsigned short bf16_bits(float f) {
  __bf16 h = (__bf16)f;
  return __builtin_bit_cast(unsigned short, h);
}

DEVI void gl_lds16(const void* g, void* l) {
  __builtin_amdgcn_global_load_lds(
      (const __attribute__((address_space(1))) void*)g,
      (__attribute__((address_space(3))) void*)l, 16, 0, 0);
}

DEVI f32x4 mfma16x16(bf16x8 a, bf16x8 b, f32x4 c) {
  return __builtin_amdgcn_mfma_f32_16x16x32_bf16(a, b, c, 0, 0, 0);
}

DEVI f32x16 mfma32(bf16x8 a, bf16x8 b, f32x16 c) {
  return __builtin_amdgcn_mfma_f32_32x32x16_bf16(a, b, c, 0, 0, 0);
}

DEVI unsigned cvtpk_bf16(float lo, float hi2) {
  unsigned r;
  asm("v_cvt_pk_bf16_f32 %0, %1, %2" : "=v"(r) : "v"(lo), "v"(hi2));
  return r;
}

// Armored: s_nop covers potential VALU<->permlane wait-state hazard that the
// compiler can't insert around an opaque INLINEASM (theory from r3/r4 fails).
DEVI void pl32swap(unsigned& a, unsigned& b) {
  asm volatile("s_nop 1\nv_permlane32_swap_b32 %0, %1\ns_nop 1"
               : "+v"(a), "+v"(b));
}

#define WAITVM0 asm volatile("s_waitcnt vmcnt(0)" ::: "memory")

// ---------------------------------------------------------------- LayerNorm
__global__ __launch_bounds__(256) void ln_kernel(
    const float* __restrict__ x, const float* __restrict__ gamma,
    const float* __restrict__ beta, __bf16* __restrict__ xn) {
  int row = blockIdx.x;
  int t = threadIdx.x;
  float4 v = ((const float4*)(x + (size_t)row * 1024))[t];
  float s = v.x + v.y + v.z + v.w;
  float sq = v.x * v.x + v.y * v.y + v.z * v.z + v.w * v.w;
#pragma unroll
  for (int off = 32; off > 0; off >>= 1) {
    s += __shfl_down(s, off);
    sq += __shfl_down(sq, off);
  }
  __shared__ float red[8];
  int w = t >> 6, ln = t & 63;
  if (ln == 0) { red[w] = s; red[4 + w] = sq; }
  __syncthreads();
  s = red[0] + red[1] + red[2] + red[3];
  sq = red[4] + red[5] + red[6] + red[7];
  float mu = s * (1.0f / 1024.0f);
  float var = sq * (1.0f / 1024.0f) - mu * mu;
  float rstd = rsqrtf(var + 1e-5f);
  float4 g = ((const float4*)gamma)[t];
  float4 b = ((const float4*)beta)[t];
  u16x4 o;
  o[0] = bf16_bits((v.x - mu) * rstd * g.x + b.x);
  o[1] = bf16_bits((v.y - mu) * rstd * g.y + b.y);
  o[2] = bf16_bits((v.z - mu) * rstd * g.z + b.z);
  o[3] = bf16_bits((v.w - mu) * rstd * g.w + b.w);
  *(u16x4*)(xn + (size_t)row * 1024 + t * 4) = o;
}

// -------------------------------------------- transpose fp32 [R][C] -> bf16 [C][R]
__global__ __launch_bounds__(256) void transpose_bf16_kernel(
    const float* __restrict__ in, __bf16* __restrict__ out, int R, int C) {
  __shared__ float tile[64][65];
  int tx = threadIdx.x & 15, ty = threadIdx.x >> 4;
  int c0 = blockIdx.x * 64, r0 = blockIdx.y * 64;
#pragma unroll
  for (int p = 0; p < 4; ++p) {
    int r = ty + p * 16;
    float4 v = *(const float4*)(in + (size_t)(r0 + r) * C + c0 + tx * 4);
    tile[r][tx * 4 + 0] = v.x;
    tile[r][tx * 4 + 1] = v.y;
    tile[r][tx * 4 + 2] = v.z;
    tile[r][tx * 4 + 3] = v.w;
  }
  __syncthreads();
#pragma unroll
  for (int p = 0; p < 4; ++p) {
    int cc = ty + p * 16;
    u16x4 o;
    o[0] = bf16_bits(tile[tx * 4 + 0][cc]);
    o[1] = bf16_bits(tile[tx * 4 + 1][cc]);
    o[2] = bf16_bits(tile[tx * 4 + 2][cc]);
    o[3] = bf16_bits(tile[tx * 4 + 3][cc]);
    *(u16x4*)(out + (size_t)(c0 + cc) * R + r0 + tx * 4) = o;
  }
}

// ---------------------------------------------------------------- GEMM
template <int EPI>
__global__ __launch_bounds__(256) void gemm_kernel(
    const __bf16* __restrict__ A, const __bf16* __restrict__ BT,
    float* __restrict__ Cout, const float* __restrict__ bias,
    __bf16* __restrict__ Qb, __bf16* __restrict__ Kb, __bf16* __restrict__ VTb) {
  __shared__ __align__(16) __bf16 Asm[128 * 32];
  __shared__ __align__(16) __bf16 Bsm[128 * 32];
  const int KD = 1024;
  int t = threadIdx.x;
  int w = t >> 6, ln = t & 63;
  int wr = w >> 1, wc = w & 1;
  int m0 = blockIdx.y * 128, n0 = blockIdx.x * 128;
  f32x4 acc[4][4] = {};

  int srow = w * 16 + (ln >> 2);
  int scol = (ln & 3) * 8;
  int lrow = ln & 15;
  int lkb = (ln >> 4) * 16;

  for (int kk = 0; kk < KD; kk += 32) {
    __syncthreads();
#pragma unroll
    for (int i = 0; i < 2; ++i) {
      int row = i * 64 + srow;
      gl_lds16(A + (size_t)(m0 + row) * KD + kk + scol,
               (char*)Asm + i * 4096 + w * 1024);
      gl_lds16(BT + (size_t)(n0 + row) * KD + kk + scol,
               (char*)Bsm + i * 4096 + w * 1024);
    }
    __syncthreads();
    bf16x8 af[4], bfr[4];
#pragma unroll
    for (int mi = 0; mi < 4; ++mi)
      af[mi] = *(const bf16x8*)((char*)Asm + (wr * 64 + mi * 16 + lrow) * 64 + lkb);
#pragma unroll
    for (int ni = 0; ni < 4; ++ni)
      bfr[ni] = *(const bf16x8*)((char*)Bsm + (wc * 64 + ni * 16 + lrow) * 64 + lkb);
#pragma unroll
    for (int mi = 0; mi < 4; ++mi)
#pragma unroll
      for (int ni = 0; ni < 4; ++ni)
        acc[mi][ni] = mfma16x16(af[mi], bfr[ni], acc[mi][ni]);
  }

  int r4 = (ln >> 4) * 4;
#pragma unroll
  for (int mi = 0; mi < 4; ++mi) {
#pragma unroll
    for (int ni = 0; ni < 4; ++ni) {
      int grow = m0 + wr * 64 + mi * 16 + r4;
      int gcol = n0 + wc * 64 + ni * 16 + lrow;
      if (EPI == 0) {
        int sel = gcol >> 10;
        int nl = gcol & 1023;
        int h = nl >> 6, d = nl & 63;
        int b = grow >> 11, seq = grow & 2047;
        int bh = b * 16 + h;
        if (sel < 2) {
          __bf16* dst = (sel == 0 ? Qb : Kb) + ((size_t)bh * 2048 + seq) * 64 + d;
#pragma unroll
          for (int r = 0; r < 4; ++r) dst[(size_t)r * 64] = (__bf16)acc[mi][ni][r];
        } else {
          u16x4 o;
          o[0] = bf16_bits(acc[mi][ni][0]);
          o[1] = bf16_bits(acc[mi][ni][1]);
          o[2] = bf16_bits(acc[mi][ni][2]);
          o[3] = bf16_bits(acc[mi][ni][3]);
          *(u16x4*)(VTb + ((size_t)bh * 64 + d) * 2048 + seq) = o;
        }
      } else {
        float bv = bias[gcol];
#pragma unroll
        for (int r = 0; r < 4; ++r)
          Cout[(size_t)(grow + r) * 1024 + gcol] = acc[mi][ni][r] + bv;
      }
    }
  }
}

// ---------------------------------------------------------------- attention
// Round-2 verified structure (4 waves x 32 q-rows, KVBLK=64, dbuf K/V,
// swapped QK^T, in-register softmax, shfl_xor cross-half exchange).
// Round-5 graft: setprio around MFMA clusters ONLY; pl32swap armored.
__global__ __launch_bounds__(256, 2) void attn_kernel(
    const __bf16* __restrict__ Qb, const __bf16* __restrict__ Kb,
    const __bf16* __restrict__ VTb, __bf16* __restrict__ sa) {
  __shared__ __align__(16) char Klds[16384];   // 2 bufs x [64 j][128B], swizzled
  __shared__ __align__(16) char Vlds[16384];   // 2 bufs x [64 d][128B], swizzled
  const float SCALE = 0.125f;
  const float LOG2E = 1.44269504f;
  const float K1 = SCALE * LOG2E;
  int t = threadIdx.x, w = t >> 6, ln = t & 63;
  int hi = ln >> 5, col = ln & 31;
  int bh = blockIdx.y, bq = bh >> 4, h = bh & 15;
  int q0 = blockIdx.x * 128;
  const __bf16* Qh = Qb + (size_t)bh * 2048 * 64;
  const __bf16* Kh = Kb + (size_t)bh * 2048 * 64;
  const __bf16* Vh = VTb + (size_t)bh * 64 * 2048;

  // Q B-frags: lane: i = col, d = dk*16 + hi*8 + 0..7
  bf16x8 qf[4];
  int qrow = q0 + w * 32 + col;
#pragma unroll
  for (int dk = 0; dk < 4; ++dk)
    qf[dk] = *(const bf16x8*)(Qh + (size_t)qrow * 64 + dk * 16 + hi * 8);

  f32x16 oacc0 = {}, oacc1 = {};
  float m_run = -1e30f, l_run = 0.f;

  // staging: thread covers phys bytes t*16 and t*16+4096 of an 8KB tile.
  int sj0 = t >> 3, sc0 = (t & 7) ^ (sj0 & 7);
  int sj1 = 32 + (t >> 3), sc1 = (t & 7) ^ (sj1 & 7);

#define STAGE(off, j0_)                                                        \
  do {                                                                         \
    gl_lds16(Kh + (size_t)((j0_) + sj0) * 64 + sc0 * 8, Klds + (off) + w * 1024); \
    gl_lds16(Kh + (size_t)((j0_) + sj1) * 64 + sc1 * 8,                        \
             Klds + (off) + 4096 + w * 1024);                                  \
    gl_lds16(Vh + (size_t)sj0 * 2048 + (j0_) + sc0 * 8, Vlds + (off) + w * 1024); \
    gl_lds16(Vh + (size_t)sj1 * 2048 + (j0_) + sc1 * 8,                        \
             Vlds + (off) + 4096 + w * 1024);                                  \
  } while (0)

  int cur = 0;
  STAGE(0, 0);
  WAITVM0;
  __builtin_amdgcn_s_barrier();
  __builtin_amdgcn_sched_barrier(0);

  for (int jt = 0; jt < 32; ++jt) {
    if (jt < 31) STAGE((cur ^ 1) * 8192, (jt + 1) * 64);
    const char* Kc = Klds + cur * 8192;
    const char* Vc = Vlds + cur * 8192;

    // QK^T: sfr[s] = S^T[j = 32s + crow(r,hi)][i = col]
    f32x16 sfr0 = {}, sfr1 = {};
    __builtin_amdgcn_s_setprio(1);
#pragma unroll
    for (int dk = 0; dk < 4; ++dk) {
      int sw = ((dk * 32 + hi * 16) ^ ((col & 7) << 4));
      bf16x8 kf0 = *(const bf16x8*)(Kc + col * 128 + sw);
      bf16x8 kf1 = *(const bf16x8*)(Kc + (32 + col) * 128 + sw);
      sfr0 = mfma32(kf0, qf[dk], sfr0);
      sfr1 = mfma32(kf1, qf[dk], sfr1);
    }
    __builtin_amdgcn_s_setprio(0);

    // in-register row max (32 vals) + one cross-half exchange (shfl, verified)
    float t8[8];
#pragma unroll
    for (int r = 0; r < 8; ++r)
      t8[r] = fmaxf(fmaxf(sfr0[r], sfr0[r + 8]), fmaxf(sfr1[r], sfr1[r + 8]));
    float mx = fmaxf(fmaxf(fmaxf(t8[0], t8[1]), fmaxf(t8[2], t8[3])),
                     fmaxf(fmaxf(t8[4], t8[5]), fmaxf(t8[6], t8[7])));
    mx = fmaxf(mx, __shfl_xor(mx, 32));
    float pmax = mx * SCALE;

    // defer-max (T13, THR=8)
    if (__any(pmax > m_run + 8.0f)) {
      float mnew = fmaxf(m_run, pmax);
      float corr = __builtin_amdgcn_exp2f((m_run - mnew) * LOG2E);
      l_run *= corr;
#pragma unroll
      for (int r = 0; r < 16; ++r) { oacc0[r] *= corr; oacc1[r] *= corr; }
      m_run = mnew;
    }
    float mb = -m_run * LOG2E;

    // P = exp, pack to bf16 PV B-frags via cvt_pk + permlane32_swap (T12)
    float psum = 0.f;
    bf16x8 pfr[4];
#pragma unroll
    for (int jk = 0; jk < 4; ++jk) {
      float p[8];
#pragma unroll
      for (int c = 0; c < 8; ++c) {
        float sv = (jk < 2) ? sfr0[(jk & 1) * 8 + c] : sfr1[(jk & 1) * 8 + c];
        p[c] = __builtin_amdgcn_exp2f(fmaf(sv, K1, mb));
      }
      psum += ((p[0] + p[1]) + (p[2] + p[3])) + ((p[4] + p[5]) + (p[6] + p[7]));
      unsigned X0 = cvtpk_bf16(p[0], p[1]);
      unsigned X1 = cvtpk_bf16(p[2], p[3]);
      unsigned Y0 = cvtpk_bf16(p[4], p[5]);
      unsigned Y1 = cvtpk_bf16(p[6], p[7]);
      pl32swap(X0, Y0);
      pl32swap(X1, Y1);
      union { unsigned u[4]; bf16x8 v; } pu;
      pu.u[0] = X0; pu.u[1] = X1; pu.u[2] = Y0; pu.u[3] = Y1;
      pfr[jk] = pu.v;
    }
    psum += __shfl_xor(psum, 32);
    l_run += psum;

    // PV: O^T[d][i] += V^T[d][j] P^T[j][i]
    __builtin_amdgcn_s_setprio(1);
#pragma unroll
    for (int jk = 0; jk < 4; ++jk) {
      int sw = ((jk * 32 + hi * 16) ^ ((col & 7) << 4));
      bf16x8 vf0 = *(const bf16x8*)(Vc + col * 128 + sw);
      bf16x8 vf1 = *(const bf16x8*)(Vc + (32 + col) * 128 + sw);
      oacc0 = mfma32(vf0, pfr[jk], oacc0);
      oacc1 = mfma32(vf1, pfr[jk], oacc1);
    }
    __builtin_amdgcn_s_setprio(0);

    WAITVM0;
    __builtin_amdgcn_s_barrier();
    __builtin_amdgcn_sched_barrier(0);
    cur ^= 1;
  }
#undef STAGE

  // epilogue: normalize, transpose O^T -> O via per-wave LDS, coalesced store
  float linv = 1.0f / l_run;
  char* Ow = Klds + w * 4096;  // [32 i][128B d-row], swizzled
#pragma unroll
  for (int da = 0; da < 2; ++da) {
    const f32x16& oa = da ? oacc1 : oacc0;
#pragma unroll
    for (int g = 0; g < 4; ++g) {
      unsigned w0 = cvtpk_bf16(oa[g * 4 + 0] * linv, oa[g * 4 + 1] * linv);
      unsigned w1 = cvtpk_bf16(oa[g * 4 + 2] * linv, oa[g * 4 + 3] * linv);
      int dby = da * 64 + g * 16 + hi * 8;
      char* dst = Ow + col * 128 + ((dby & ~15) ^ ((col & 7) << 4)) + (dby & 8);
      u32x2 pr = {w0, w1};
      *(u32x2*)dst = pr;
    }
  }
  int rr0 = ln >> 3, c16o = ln & 7;
#pragma unroll
  for (int pp = 0; pp < 4; ++pp) {
    int rr = rr0 + pp * 8;
    bf16x8 ov = *(const bf16x8*)(Ow + rr * 128 + ((c16o * 16) ^ ((rr & 7) << 4)));
    int grow = bq * 2048 + q0 + w * 32 + rr;
    *(bf16x8*)(sa + (size_t)grow * 1024 + h * 64 + c16o * 8) = ov;
  }
}

// ---------------------------------------------------------------- launch
extern "C" void kernel_launch(void* const* d_in, const int* in_sizes, int n_in,
                              void* d_out, int out_size, void* d_ws, size_t ws_size,
                              hipStream_t stream) {
  const float* x = (const float*)d_in[0];
  const float* gamma = (const float*)d_in[1];
  const float* beta = (const float*)d_in[2];
  const float* w_qkv = (const float*)d_in[3];
  const float* w_out = (const float*)d_in[4];
  const float* b_out = (const float*)d_in[5];

  char* ws = (char*)d_ws;
  __bf16* xn = (__bf16*)(ws);                       // 8 MB (reused as sa)
  __bf16* wqkvT = (__bf16*)(ws + (8l << 20));       // 6 MB
  __bf16* woutT = (__bf16*)(ws + (14l << 20));      // 2 MB
  __bf16* Qb = (__bf16*)(ws + (16l << 20));         // 8 MB
  __bf16* Kb = (__bf16*)(ws + (24l << 20));         // 8 MB
  __bf16* VTb = (__bf16*)(ws + (32l << 20));        // 8 MB
  __bf16* sa = xn;                                  // xn dead after QKV GEMM

  ln_kernel<<<4096, 256, 0, stream>>>(x, gamma, beta, xn);
  transpose_bf16_kernel<<<dim3(48, 16), 256, 0, stream>>>(w_qkv, wqkvT, 1024, 3072);
  transpose_bf16_kernel<<<dim3(16, 16), 256, 0, stream>>>(w_out, woutT, 1024, 1024);
  gemm_kernel<0><<<dim3(24, 32), 256, 0, stream>>>(xn, wqkvT, nullptr, nullptr,
                                                   Qb, Kb, VTb);
  attn_kernel<<<dim3(16, 32), 256, 0, stream>>>(Qb, Kb, VTb, sa);
  gemm_kernel<1><<<dim3(8, 32), 256, 0, stream>>>(sa, woutT, (float*)d_out, b_out,
                                                  nullptr, nullptr, nullptr);
}

// Round 6
// 127.132 us; speedup vs baseline: 1.0350x; 1.0350x over previous
//
#include <hip/hip_runtime.h>

typedef __attribute__((ext_vector_type(4))) float f32x4;
typedef __attribute__((ext_vector_type(16))) float f32x16;
typedef __attribute__((ext_vector_type(8))) __bf16 bf16x8;
typedef __attribute__((ext_vector_type(4))) unsigned short u16x4;
typedef __attribute__((ext_vector_type(2))) unsigned int u32x2;

#define DEVI static __device__ __forceinline__

DEVI unsigned short bf16_bits(float f) {
  __bf16 h = (__bf16)f;
  return __builtin_bit_cast(unsigned short, h);
}

DEVI void gl_lds16(const void* g, void* l) {
  __builtin_amdgcn_global_load_lds(
      (const __attribute__((address_space(1))) void*)g,
      (__attribute__((address_space(3))) void*)l, 16, 0, 0);
}

DEVI f32x4 mfma16x16(bf16x8 a, bf16x8 b, f32x4 c) {
  return __builtin_amdgcn_mfma_f32_16x16x32_bf16(a, b, c, 0, 0, 0);
}

DEVI f32x16 mfma32(bf16x8 a, bf16x8 b, f32x16 c) {
  return __builtin_amdgcn_mfma_f32_32x32x16_bf16(a, b, c, 0, 0, 0);
}

DEVI unsigned cvtpk_bf16(float lo, float hi2) {
  unsigned r;
  asm("v_cvt_pk_bf16_f32 %0, %1, %2" : "=v"(r) : "v"(lo), "v"(hi2));
  return r;
}

// NOTE (r3/r4 lesson): never call with two copies of the same value — the
// allocator may coalesce them into ONE register and the swap degenerates.
// Only used with distinct values (P-pack). s_nop armor kept (verified in r5).
DEVI void pl32swap(unsigned& a, unsigned& b) {
  asm volatile("s_nop 1\nv_permlane32_swap_b32 %0, %1\ns_nop 1"
               : "+v"(a), "+v"(b));
}

// ---------------------------------------------------------------- LayerNorm
__global__ __launch_bounds__(256) void ln_kernel(
    const float* __restrict__ x, const float* __restrict__ gamma,
    const float* __restrict__ beta, __bf16* __restrict__ xn) {
  int row = blockIdx.x;
  int t = threadIdx.x;
  float4 v = ((const float4*)(x + (size_t)row * 1024))[t];
  float s = v.x + v.y + v.z + v.w;
  float sq = v.x * v.x + v.y * v.y + v.z * v.z + v.w * v.w;
#pragma unroll
  for (int off = 32; off > 0; off >>= 1) {
    s += __shfl_down(s, off);
    sq += __shfl_down(sq, off);
  }
  __shared__ float red[8];
  int w = t >> 6, ln = t & 63;
  if (ln == 0) { red[w] = s; red[4 + w] = sq; }
  __syncthreads();
  s = red[0] + red[1] + red[2] + red[3];
  sq = red[4] + red[5] + red[6] + red[7];
  float mu = s * (1.0f / 1024.0f);
  float var = sq * (1.0f / 1024.0f) - mu * mu;
  float rstd = rsqrtf(var + 1e-5f);
  float4 g = ((const float4*)gamma)[t];
  float4 b = ((const float4*)beta)[t];
  u16x4 o;
  o[0] = bf16_bits((v.x - mu) * rstd * g.x + b.x);
  o[1] = bf16_bits((v.y - mu) * rstd * g.y + b.y);
  o[2] = bf16_bits((v.z - mu) * rstd * g.z + b.z);
  o[3] = bf16_bits((v.w - mu) * rstd * g.w + b.w);
  *(u16x4*)(xn + (size_t)row * 1024 + t * 4) = o;
}

// -------------------------------------------- transpose fp32 [R][C] -> bf16 [C][R]
__global__ __launch_bounds__(256) void transpose_bf16_kernel(
    const float* __restrict__ in, __bf16* __restrict__ out, int R, int C) {
  __shared__ float tile[64][65];
  int tx = threadIdx.x & 15, ty = threadIdx.x >> 4;
  int c0 = blockIdx.x * 64, r0 = blockIdx.y * 64;
#pragma unroll
  for (int p = 0; p < 4; ++p) {
    int r = ty + p * 16;
    float4 v = *(const float4*)(in + (size_t)(r0 + r) * C + c0 + tx * 4);
    tile[r][tx * 4 + 0] = v.x;
    tile[r][tx * 4 + 1] = v.y;
    tile[r][tx * 4 + 2] = v.z;
    tile[r][tx * 4 + 3] = v.w;
  }
  __syncthreads();
#pragma unroll
  for (int p = 0; p < 4; ++p) {
    int cc = ty + p * 16;
    u16x4 o;
    o[0] = bf16_bits(tile[tx * 4 + 0][cc]);
    o[1] = bf16_bits(tile[tx * 4 + 1][cc]);
    o[2] = bf16_bits(tile[tx * 4 + 2][cc]);
    o[3] = bf16_bits(tile[tx * 4 + 3][cc]);
    *(u16x4*)(out + (size_t)(c0 + cc) * R + r0 + tx * 4) = o;
  }
}

// ---------------------------------------------------------------- GEMM
template <int EPI>
__global__ __launch_bounds__(256) void gemm_kernel(
    const __bf16* __restrict__ A, const __bf16* __restrict__ BT,
    float* __restrict__ Cout, const float* __restrict__ bias,
    __bf16* __restrict__ Qb, __bf16* __restrict__ Kb, __bf16* __restrict__ VTb) {
  __shared__ __align__(16) __bf16 Asm[128 * 32];
  __shared__ __align__(16) __bf16 Bsm[128 * 32];
  const int KD = 1024;
  int t = threadIdx.x;
  int w = t >> 6, ln = t & 63;
  int wr = w >> 1, wc = w & 1;
  int m0 = blockIdx.y * 128, n0 = blockIdx.x * 128;
  f32x4 acc[4][4] = {};

  int srow = w * 16 + (ln >> 2);
  int scol = (ln & 3) * 8;
  int lrow = ln & 15;
  int lkb = (ln >> 4) * 16;

  for (int kk = 0; kk < KD; kk += 32) {
    __syncthreads();
#pragma unroll
    for (int i = 0; i < 2; ++i) {
      int row = i * 64 + srow;
      gl_lds16(A + (size_t)(m0 + row) * KD + kk + scol,
               (char*)Asm + i * 4096 + w * 1024);
      gl_lds16(BT + (size_t)(n0 + row) * KD + kk + scol,
               (char*)Bsm + i * 4096 + w * 1024);
    }
    __syncthreads();
    bf16x8 af[4], bfr[4];
#pragma unroll
    for (int mi = 0; mi < 4; ++mi)
      af[mi] = *(const bf16x8*)((char*)Asm + (wr * 64 + mi * 16 + lrow) * 64 + lkb);
#pragma unroll
    for (int ni = 0; ni < 4; ++ni)
      bfr[ni] = *(const bf16x8*)((char*)Bsm + (wc * 64 + ni * 16 + lrow) * 64 + lkb);
#pragma unroll
    for (int mi = 0; mi < 4; ++mi)
#pragma unroll
      for (int ni = 0; ni < 4; ++ni)
        acc[mi][ni] = mfma16x16(af[mi], bfr[ni], acc[mi][ni]);
  }

  int r4 = (ln >> 4) * 4;
#pragma unroll
  for (int mi = 0; mi < 4; ++mi) {
#pragma unroll
    for (int ni = 0; ni < 4; ++ni) {
      int grow = m0 + wr * 64 + mi * 16 + r4;
      int gcol = n0 + wc * 64 + ni * 16 + lrow;
      if (EPI == 0) {
        int sel = gcol >> 10;
        int nl = gcol & 1023;
        int h = nl >> 6, d = nl & 63;
        int b = grow >> 11, seq = grow & 2047;
        int bh = b * 16 + h;
        if (sel < 2) {
          __bf16* dst = (sel == 0 ? Qb : Kb) + ((size_t)bh * 2048 + seq) * 64 + d;
#pragma unroll
          for (int r = 0; r < 4; ++r) dst[(size_t)r * 64] = (__bf16)acc[mi][ni][r];
        } else {
          u16x4 o;
          o[0] = bf16_bits(acc[mi][ni][0]);
          o[1] = bf16_bits(acc[mi][ni][1]);
          o[2] = bf16_bits(acc[mi][ni][2]);
          o[3] = bf16_bits(acc[mi][ni][3]);
          *(u16x4*)(VTb + ((size_t)bh * 64 + d) * 2048 + seq) = o;
        }
      } else {
        float bv = bias[gcol];
#pragma unroll
        for (int r = 0; r < 4; ++r)
          Cout[(size_t)(grow + r) * 1024 + gcol] = acc[mi][ni][r] + bv;
      }
    }
  }
}

// ---------------------------------------------------------------- attention
// Round-2 verified compute structure (4 waves x 32 q-rows, swapped QK^T,
// in-register softmax, shfl_xor cross-half, pl32swap only in P-pack).
// Round-6 change: 3-buffer K/V pipeline, counted vmcnt(4) (T4) — loads for
// tile jt issued 2 iterations ahead; never drain vmcnt to 0 in the loop.
__global__ __launch_bounds__(256, 2) void attn_kernel(
    const __bf16* __restrict__ Qb, const __bf16* __restrict__ Kb,
    const __bf16* __restrict__ VTb, __bf16* __restrict__ sa) {
  __shared__ __align__(16) char Klds[24576];   // 3 bufs x [64 j][128B], swizzled
  __shared__ __align__(16) char Vlds[24576];   // 3 bufs x [64 d][128B], swizzled
  const float SCALE = 0.125f;
  const float LOG2E = 1.44269504f;
  const float K1 = SCALE * LOG2E;
  int t = threadIdx.x, w = t >> 6, ln = t & 63;
  int hi = ln >> 5, col = ln & 31;
  int bh = blockIdx.y, bq = bh >> 4, h = bh & 15;
  int q0 = blockIdx.x * 128;
  const __bf16* Qh = Qb + (size_t)bh * 2048 * 64;
  const __bf16* Kh = Kb + (size_t)bh * 2048 * 64;
  const __bf16* Vh = VTb + (size_t)bh * 64 * 2048;

  // Q B-frags: lane: i = col, d = dk*16 + hi*8 + 0..7
  bf16x8 qf[4];
  int qrow = q0 + w * 32 + col;
#pragma unroll
  for (int dk = 0; dk < 4; ++dk)
    qf[dk] = *(const bf16x8*)(Qh + (size_t)qrow * 64 + dk * 16 + hi * 8);

  f32x16 oacc0 = {}, oacc1 = {};
  float m_run = -1e30f, l_run = 0.f;

  // staging: thread covers phys bytes t*16 and t*16+4096 of an 8KB tile.
  int sj0 = t >> 3, sc0 = (t & 7) ^ (sj0 & 7);
  int sj1 = 32 + (t >> 3), sc1 = (t & 7) ^ (sj1 & 7);

#define STAGE(off, j0_)                                                        \
  do {                                                                         \
    gl_lds16(Kh + (size_t)((j0_) + sj0) * 64 + sc0 * 8, Klds + (off) + w * 1024); \
    gl_lds16(Kh + (size_t)((j0_) + sj1) * 64 + sc1 * 8,                        \
             Klds + (off) + 4096 + w * 1024);                                  \
    gl_lds16(Vh + (size_t)sj0 * 2048 + (j0_) + sc0 * 8, Vlds + (off) + w * 1024); \
    gl_lds16(Vh + (size_t)sj1 * 2048 + (j0_) + sc1 * 8,                        \
             Vlds + (off) + 4096 + w * 1024);                                  \
  } while (0)

  STAGE(0, 0);        // tile 0 -> buf 0
  STAGE(8192, 64);    // tile 1 -> buf 1

  int cb = 0;   // buffer holding tile jt
  int sb = 2;   // buffer to stage tile jt+2 into

  for (int jt = 0; jt < 32; ++jt) {
    // retire tile jt's 4 loads; leave tile jt+1's in flight (T4: never 0)
    if (jt < 31) {
      asm volatile("s_waitcnt vmcnt(4)" ::: "memory");
    } else {
      asm volatile("s_waitcnt vmcnt(0)" ::: "memory");
    }
    __builtin_amdgcn_s_barrier();
    __builtin_amdgcn_sched_barrier(0);

    const char* Kc = Klds + cb * 8192;
    const char* Vc = Vlds + cb * 8192;

    // QK^T: sfr[s] = S^T[j = 32s + crow(r,hi)][i = col]
    f32x16 sfr0 = {}, sfr1 = {};
#pragma unroll
    for (int dk = 0; dk < 4; ++dk) {
      int sw = ((dk * 32 + hi * 16) ^ ((col & 7) << 4));
      bf16x8 kf0 = *(const bf16x8*)(Kc + col * 128 + sw);
      bf16x8 kf1 = *(const bf16x8*)(Kc + (32 + col) * 128 + sw);
      sfr0 = mfma32(kf0, qf[dk], sfr0);
      sfr1 = mfma32(kf1, qf[dk], sfr1);
    }

    // in-register row max (32 vals) + one cross-half exchange (shfl, verified)
    float t8[8];
#pragma unroll
    for (int r = 0; r < 8; ++r)
      t8[r] = fmaxf(fmaxf(sfr0[r], sfr0[r + 8]), fmaxf(sfr1[r], sfr1[r + 8]));
    float mx = fmaxf(fmaxf(fmaxf(t8[0], t8[1]), fmaxf(t8[2], t8[3])),
                     fmaxf(fmaxf(t8[4], t8[5]), fmaxf(t8[6], t8[7])));
    mx = fmaxf(mx, __shfl_xor(mx, 32));
    float pmax = mx * SCALE;

    // defer-max (T13, THR=8)
    if (__any(pmax > m_run + 8.0f)) {
      float mnew = fmaxf(m_run, pmax);
      float corr = __builtin_amdgcn_exp2f((m_run - mnew) * LOG2E);
      l_run *= corr;
#pragma unroll
      for (int r = 0; r < 16; ++r) { oacc0[r] *= corr; oacc1[r] *= corr; }
      m_run = mnew;
    }
    float mb = -m_run * LOG2E;

    // P = exp, pack to bf16 PV B-frags via cvt_pk + permlane32_swap (T12)
    float psum = 0.f;
    bf16x8 pfr[4];
#pragma unroll
    for (int jk = 0; jk < 4; ++jk) {
      float p[8];
#pragma unroll
      for (int c = 0; c < 8; ++c) {
        float sv = (jk < 2) ? sfr0[(jk & 1) * 8 + c] : sfr1[(jk & 1) * 8 + c];
        p[c] = __builtin_amdgcn_exp2f(fmaf(sv, K1, mb));
      }
      psum += ((p[0] + p[1]) + (p[2] + p[3])) + ((p[4] + p[5]) + (p[6] + p[7]));
      unsigned X0 = cvtpk_bf16(p[0], p[1]);
      unsigned X1 = cvtpk_bf16(p[2], p[3]);
      unsigned Y0 = cvtpk_bf16(p[4], p[5]);
      unsigned Y1 = cvtpk_bf16(p[6], p[7]);
      pl32swap(X0, Y0);
      pl32swap(X1, Y1);
      union { unsigned u[4]; bf16x8 v; } pu;
      pu.u[0] = X0; pu.u[1] = X1; pu.u[2] = Y0; pu.u[3] = Y1;
      pfr[jk] = pu.v;
    }
    psum += __shfl_xor(psum, 32);
    l_run += psum;

    // PV: O^T[d][i] += V^T[d][j] P^T[j][i]
#pragma unroll
    for (int jk = 0; jk < 4; ++jk) {
      int sw = ((jk * 32 + hi * 16) ^ ((col & 7) << 4));
      bf16x8 vf0 = *(const bf16x8*)(Vc + col * 128 + sw);
      bf16x8 vf1 = *(const bf16x8*)(Vc + (32 + col) * 128 + sw);
      oacc0 = mfma32(vf0, pfr[jk], oacc0);
      oacc1 = mfma32(vf1, pfr[jk], oacc1);
    }

    // stage tile jt+2 into buf[(jt+2)%3] (= buf[(jt-1)%3]; safe: the barrier
    // above guarantees all waves finished iteration jt-1's reads).
    if (jt < 30) STAGE(sb * 8192, (jt + 2) * 64);
    cb = (cb == 2) ? 0 : cb + 1;
    sb = (sb == 2) ? 0 : sb + 1;
  }
#undef STAGE

  // epilogue: normalize, transpose O^T -> O via per-wave LDS, coalesced store.
  // __syncthreads: buf1 aliases waves 2/3's scratch; wait for all reads.
  __syncthreads();
  float linv = 1.0f / l_run;
  char* Ow = Klds + w * 4096;  // [32 i][128B d-row], swizzled
#pragma unroll
  for (int da = 0; da < 2; ++da) {
    const f32x16& oa = da ? oacc1 : oacc0;
#pragma unroll
    for (int g = 0; g < 4; ++g) {
      unsigned w0 = cvtpk_bf16(oa[g * 4 + 0] * linv, oa[g * 4 + 1] * linv);
      unsigned w1 = cvtpk_bf16(oa[g * 4 + 2] * linv, oa[g * 4 + 3] * linv);
      int dby = da * 64 + g * 16 + hi * 8;
      char* dst = Ow + col * 128 + ((dby & ~15) ^ ((col & 7) << 4)) + (dby & 8);
      u32x2 pr = {w0, w1};
      *(u32x2*)dst = pr;
    }
  }
  int rr0 = ln >> 3, c16o = ln & 7;
#pragma unroll
  for (int pp = 0; pp < 4; ++pp) {
    int rr = rr0 + pp * 8;
    bf16x8 ov = *(const bf16x8*)(Ow + rr * 128 + ((c16o * 16) ^ ((rr & 7) << 4)));
    int grow = bq * 2048 + q0 + w * 32 + rr;
    *(bf16x8*)(sa + (size_t)grow * 1024 + h * 64 + c16o * 8) = ov;
  }
}

// ---------------------------------------------------------------- launch
extern "C" void kernel_launch(void* const* d_in, const int* in_sizes, int n_in,
                              void* d_out, int out_size, void* d_ws, size_t ws_size,
                              hipStream_t stream) {
  const float* x = (const float*)d_in[0];
  const float* gamma = (const float*)d_in[1];
  const float* beta = (const float*)d_in[2];
  const float* w_qkv = (const float*)d_in[3];
  const float* w_out = (const float*)d_in[4];
  const float* b_out = (const float*)d_in[5];

  char* ws = (char*)d_ws;
  __bf16* xn = (__bf16*)(ws);                       // 8 MB (reused as sa)
  __bf16* wqkvT = (__bf16*)(ws + (8l << 20));       // 6 MB
  __bf16* woutT = (__bf16*)(ws + (14l << 20));      // 2 MB
  __bf16* Qb = (__bf16*)(ws + (16l << 20));         // 8 MB
  __bf16* Kb = (__bf16*)(ws + (24l << 20));         // 8 MB
  __bf16* VTb = (__bf16*)(ws + (32l << 20));        // 8 MB
  __bf16* sa = xn;                                  // xn dead after QKV GEMM

  ln_kernel<<<4096, 256, 0, stream>>>(x, gamma, beta, xn);
  transpose_bf16_kernel<<<dim3(48, 16), 256, 0, stream>>>(w_qkv, wqkvT, 1024, 3072);
  transpose_bf16_kernel<<<dim3(16, 16), 256, 0, stream>>>(w_out, woutT, 1024, 1024);
  gemm_kernel<0><<<dim3(24, 32), 256, 0, stream>>>(xn, wqkvT, nullptr, nullptr,
                                                   Qb, Kb, VTb);
  attn_kernel<<<dim3(16, 32), 256, 0, stream>>>(Qb, Kb, VTb, sa);
  gemm_kernel<1><<<dim3(8, 32), 256, 0, stream>>>(sa, woutT, (float*)d_out, b_out,
                                                  nullptr, nullptr, nullptr);
}